// Round 14
// baseline (67.701 us; speedup 1.0000x reference)
//
#include <hip/hip_runtime.h>

// x[2][4][128][128][128] f32, y[2][1][128][128][128] int32
constexpr int SPB = 1 << 21;
constexpr float EPSV = 1e-6f;

// Static scratch: packed per-voxel mask, 4 MB.
// mask[v] = (center_class << 4) | OR_{3x3x3 clipped}(1 << y[v+d])
__device__ unsigned char g_mask[2 * SPB];

// ===========================================================================
// K0: build packed 27-neighborhood presence mask + center class (proven R5)
// ===========================================================================
constexpr int K0_ZSEG = 4;
constexpr int K0_NBLK = (2 * (128 / K0_ZSEG) * 128) / 4;  // 2048

struct MEnt { int pk, cx, cy; };

__device__ __forceinline__ MEnt k0_load(const int* __restrict__ yb, int s,
                                        int rbase0, bool ym1, bool yp1) {
    MEnt e;
    const int rb = (s << 14) | rbase0;
    int2 vc = *(const int2*)(yb + rb);
    int nib0 = 1 << vc.x, nib1 = 1 << vc.y;
    if (ym1) { int2 vm = *(const int2*)(yb + rb - 128); nib0 |= 1 << vm.x; nib1 |= 1 << vm.y; }
    if (yp1) { int2 vp = *(const int2*)(yb + rb + 128); nib0 |= 1 << vp.x; nib1 |= 1 << vp.y; }
    e.pk = nib0 | (nib1 << 8);
    e.cx = vc.x; e.cy = vc.y;
    return e;
}

__global__ __launch_bounds__(256) void mask_build(const int* __restrict__ y32) {
    const int wid = (blockIdx.x << 2) | (threadIdx.x >> 6);
    const int lane = threadIdx.x & 63;
    const int yy = wid & 127;
    const int zs = (wid >> 7) & 31;
    const int b = (wid >> 12) & 1;
    const int x0 = lane << 1;
    const int z0 = zs * K0_ZSEG;
    const bool ym1 = yy > 0, yp1 = yy < 127;
    const int rbase0 = (yy << 7) | x0;

    const int* __restrict__ yb = y32 + ((long)b << 21);
    unsigned char* __restrict__ mb = g_mask + ((long)b << 21);

    MEnt e0, e1;
    if (z0 > 0) e0 = k0_load(yb, z0 - 1, rbase0, ym1, yp1);
    else { e0.pk = 0; e0.cx = 0; e0.cy = 0; }
    e1 = k0_load(yb, z0, rbase0, ym1, yp1);

#pragma unroll
    for (int dz = 0; dz < K0_ZSEG; ++dz) {
        const int z = z0 + dz;
        MEnt e2;
        if (z + 1 < 128) e2 = k0_load(yb, z + 1, rbase0, ym1, yp1);
        else { e2.pk = 0; e2.cx = 0; e2.cy = 0; }

        const int zor = e0.pk | e1.pk | e2.pk;
        int orL = __shfl_up(zor, 1);
        if (lane == 0) orL = 0;
        int orR = __shfl_down(zor, 1);
        if (lane == 63) orR = 0;
        const int full0 = (zor | (zor >> 8) | (orL >> 8)) & 15;
        const int full1 = (zor | (zor >> 8) | orR) & 15;

        const unsigned short st =
            (unsigned short)((full0 | (e1.cx << 4)) | ((full1 | (e1.cy << 4)) << 8));
        *(unsigned short*)(mb + ((z << 14) | rbase0)) = st;

        e0 = e1; e1 = e2;
    }
}

// ===========================================================================
// K1: pass12 — py[plane][z][y][x] = prod over x±1, y±1 of (1-x).
// Pure streaming: 1 float2 load + 2 shuffles + 1 float2 store per step,
// marching y (+512B/step). No LDS, no barriers. 8192 waves.
// ===========================================================================
constexpr int P12_NBLK = 2048;  // 8 planes * 128 z * 2 halves; 4 waves = 4 octs

__global__ __launch_bounds__(256) void pass12(const float* __restrict__ x,
                                              float* __restrict__ ws) {
    float* __restrict__ py = ws + 1024;
    const int bid = blockIdx.x;
    const int plane = bid & 7;            // -> XCD
    const int inner = bid >> 3;
    const int z = inner & 127;
    const int half = inner >> 7;          // 0..1
    const int w = threadIdx.x >> 6;
    const int lane = threadIdx.x & 63;
    const int y0 = (half * 4 + w) << 4;   // 16-row oct
    const int xo = lane << 1;

    const float* __restrict__ xs = x + ((long)plane << 21) + (z << 14) + xo;
    float* __restrict__ ps = py + ((long)plane << 21) + (z << 14) + xo;

    auto xprow = [&](int y) -> float2 {   // y is wave-uniform -> no divergence
        if ((unsigned)y > 127u) return make_float2(1.f, 1.f);
        const float2 v = *(const float2*)(xs + (y << 7));
        const float a0 = 1.f - v.x, a1 = 1.f - v.y;
        float lft = __shfl_up(a1, 1); if (lane == 0) lft = 1.f;
        float rgt = __shfl_down(a0, 1); if (lane == 63) rgt = 1.f;
        const float c = a0 * a1;
        return make_float2(lft * c, c * rgt);
    };

    float2 r0 = xprow(y0 - 1);
    float2 r1 = xprow(y0);
#pragma unroll
    for (int dy = 0; dy < 16; ++dy) {
        const int y = y0 + dy;
        const float2 r2 = xprow(y + 1);
        *(float2*)(ps + (y << 7)) =
            make_float2(r0.x * r1.x * r2.x, r0.y * r1.y * r2.y);
        r0 = r1; r1 = r2;
    }
}

// ===========================================================================
// K2: pass3 — marches z with a 3-row register ring of py. Exactly 3 loads
// per step (py[z+1] float2, x float2, mask ushort), no LDS/barriers/shuffles.
// ===========================================================================
constexpr int P3_NBLK = 2048;  // 8 planes * 128 y * 2 halves; 4 waves = 4 z-octs

__global__ __launch_bounds__(256) void pass3(const float* __restrict__ x,
                                             float* __restrict__ ws) {
    float* __restrict__ acc = ws;
    const float* __restrict__ py = ws + 1024;
    __shared__ float sred[4];

    const int bid = blockIdx.x;
    const int plane = bid & 7;            // -> XCD
    const int b = plane >> 2, cls = plane & 3;
    const int inner = bid >> 3;
    const int yy = inner & 127;
    const int half = inner >> 7;          // 0..1
    const int t = threadIdx.x;
    const int w = t >> 6;
    const int lane = t & 63;
    const int z0 = ((half * 4 + w) << 4); // 16-slice z-oct
    const int xo = lane << 1;

    const long pb = (long)plane << 21;
    const float* __restrict__ xs = x + pb + (yy << 7) + xo;
    const float* __restrict__ ps = py + pb + (yy << 7) + xo;
    const unsigned char* __restrict__ ms = g_mask + ((long)b << 21) + (yy << 7) + xo;

    auto pyrow = [&](int z) -> float2 {   // z wave-uniform
        if ((unsigned)z > 127u) return make_float2(1.f, 1.f);
        return *(const float2*)(ps + (z << 14));
    };

    float fp = 0.f, fn = 0.f, sx = 0.f, sy = 0.f;

    float2 r0 = pyrow(z0 - 1);
    float2 r1 = pyrow(z0);
#pragma unroll
    for (int dz = 0; dz < 16; ++dz) {
        const int z = z0 + dz;
        const float2 r2 = pyrow(z + 1);
        const float2 xv = *(const float2*)(xs + (z << 14));
        const unsigned m2 = *(const unsigned short*)(ms + (z << 14));

        const float P0 = r0.x * r1.x * r2.x;
        const float P1 = r0.y * r1.y * r2.y;

        {
            const int m = m2 & 0xFF;
            const bool pres = (m >> cls) & 1;
            const bool eq = (m >> 4) == cls;
            sx += xv.x;
            fp += eq ? 0.f : xv.x * (pres ? 1.f : 2.f);
            fn += eq ? (1.f - xv.x) * (1.f + P0) : 0.f;
            sy += eq ? 1.f : 0.f;
        }
        {
            const int m = (m2 >> 8) & 0xFF;
            const bool pres = (m >> cls) & 1;
            const bool eq = (m >> 4) == cls;
            sx += xv.y;
            fp += eq ? 0.f : xv.y * (pres ? 1.f : 2.f);
            fn += eq ? (1.f - xv.y) * (1.f + P1) : 0.f;
            sy += eq ? 1.f : 0.f;
        }

        r0 = r1; r1 = r2;
    }

    // ---- reduce 4 scalars: wave shuffle -> block LDS -> global atomics ----
    float rr4[4] = {fp, fn, sx, sy};
#pragma unroll
    for (int i = 0; i < 4; ++i) {
        float vv = rr4[i];
#pragma unroll
        for (int off = 32; off >= 1; off >>= 1) vv += __shfl_down(vv, off);
        rr4[i] = vv;
    }
    if (t < 4) sred[t] = 0.f;
    __syncthreads();
    if (lane == 0) {
#pragma unroll
        for (int i = 0; i < 4; ++i) atomicAdd(&sred[i], rr4[i]);
    }
    __syncthreads();
    if (t < 4)
        atomicAdd(&acc[b * 16 + t * 4 + cls], sred[t]);
}

// ===========================================================================
// K3: finalize scalar loss
// ===========================================================================
__global__ void lah_finalize(const float* __restrict__ acc, float* __restrict__ out) {
    float loss = 0.f;
#pragma unroll
    for (int b = 0; b < 2; ++b) {
#pragma unroll
        for (int c = 1; c < 4; ++c) {
            const float fp = acc[b * 16 + 0 + c];
            const float fn = acc[b * 16 + 4 + c];
            const float sxv = acc[b * 16 + 8 + c];
            const float syv = acc[b * 16 + 12 + c];
            loss += fmaxf(fp / (sxv + EPSV), fn / (syv + EPSV));
        }
    }
    out[0] = loss / 6.f;
}

extern "C" void kernel_launch(void* const* d_in, const int* in_sizes, int n_in,
                              void* d_out, int out_size, void* d_ws, size_t ws_size,
                              hipStream_t stream) {
    const float* x = (const float*)d_in[0];
    const int* y32 = (const int*)d_in[1];
    float* out = (float*)d_out;
    float* ws = (float*)d_ws;   // [0..31] acc; [1024..] py buffer (64 MB)

    hipMemsetAsync(d_ws, 0, 4096, stream);
    mask_build<<<K0_NBLK, 256, 0, stream>>>(y32);
    pass12<<<P12_NBLK, 256, 0, stream>>>(x, ws);
    pass3<<<P3_NBLK, 256, 0, stream>>>(x, ws);
    lah_finalize<<<1, 1, 0, stream>>>(ws, out);
}

// Round 15
// 51.903 us; speedup vs baseline: 1.3044x; 1.3044x over previous
//
#include <hip/hip_runtime.h>

// x[2][4][128][128][128] f32, y[2][1][128][128][128] int32
constexpr int SPB = 1 << 21;
constexpr float EPSV = 1e-6f;

// Static scratch: packed per-voxel mask, 4 MB.
// mask[v] = (center_class << 4) | OR_{3x3x3 clipped}(1 << y[v+d])
__device__ unsigned char g_mask[2 * SPB];

// ===========================================================================
// K0: build packed 27-neighborhood presence mask + center class (proven R5)
// ===========================================================================
constexpr int K0_ZSEG = 4;
constexpr int K0_NBLK = (2 * (128 / K0_ZSEG) * 128) / 4;  // 2048

struct MEnt { int pk, cx, cy; };

__device__ __forceinline__ MEnt k0_load(const int* __restrict__ yb, int s,
                                        int rbase0, bool ym1, bool yp1) {
    MEnt e;
    const int rb = (s << 14) | rbase0;
    int2 vc = *(const int2*)(yb + rb);
    int nib0 = 1 << vc.x, nib1 = 1 << vc.y;
    if (ym1) { int2 vm = *(const int2*)(yb + rb - 128); nib0 |= 1 << vm.x; nib1 |= 1 << vm.y; }
    if (yp1) { int2 vp = *(const int2*)(yb + rb + 128); nib0 |= 1 << vp.x; nib1 |= 1 << vp.y; }
    e.pk = nib0 | (nib1 << 8);
    e.cx = vc.x; e.cy = vc.y;
    return e;
}

__global__ __launch_bounds__(256) void mask_build(const int* __restrict__ y32) {
    const int wid = (blockIdx.x << 2) | (threadIdx.x >> 6);
    const int lane = threadIdx.x & 63;
    const int yy = wid & 127;
    const int zs = (wid >> 7) & 31;
    const int b = (wid >> 12) & 1;
    const int x0 = lane << 1;
    const int z0 = zs * K0_ZSEG;
    const bool ym1 = yy > 0, yp1 = yy < 127;
    const int rbase0 = (yy << 7) | x0;

    const int* __restrict__ yb = y32 + ((long)b << 21);
    unsigned char* __restrict__ mb = g_mask + ((long)b << 21);

    MEnt e0, e1;
    if (z0 > 0) e0 = k0_load(yb, z0 - 1, rbase0, ym1, yp1);
    else { e0.pk = 0; e0.cx = 0; e0.cy = 0; }
    e1 = k0_load(yb, z0, rbase0, ym1, yp1);

#pragma unroll
    for (int dz = 0; dz < K0_ZSEG; ++dz) {
        const int z = z0 + dz;
        MEnt e2;
        if (z + 1 < 128) e2 = k0_load(yb, z + 1, rbase0, ym1, yp1);
        else { e2.pk = 0; e2.cx = 0; e2.cy = 0; }

        const int zor = e0.pk | e1.pk | e2.pk;
        int orL = __shfl_up(zor, 1);
        if (lane == 0) orL = 0;
        int orR = __shfl_down(zor, 1);
        if (lane == 63) orR = 0;
        const int full0 = (zor | (zor >> 8) | (orL >> 8)) & 15;
        const int full1 = (zor | (zor >> 8) | orR) & 15;

        const unsigned short st =
            (unsigned short)((full0 | (e1.cx << 4)) | ((full1 | (e1.cy << 4)) << 8));
        *(unsigned short*)(mb + ((z << 14) | rbase0)) = st;

        e0 = e1; e1 = e2;
    }
}

// ===========================================================================
// K1: FLAT RECOMPUTE STENCIL — no rings, no LDS data path, no barriers.
// Wave = (plane, row y, 16-slice z-chunk). Per body: 12 INDEPENDENT float2
// loads (slices z-1..z+2 x rows y-1..y+1) -> y-products in regs -> z-product
// -> 2 x-shuffles -> accumulate 2 output slices. State ~50 VGPR -> 8 w/SIMD.
// ===========================================================================
constexpr int NBLK = 2048;   // 8 planes * 32 y-quads * 8 z-chunks

__global__ __launch_bounds__(256) void lah_flat(const float* __restrict__ x,
                                                float* __restrict__ acc) {
    __shared__ float sred[4];

    const int bid = blockIdx.x;
    const int plane = bid & 7;            // -> XCD (round-robin dispatch)
    const int b = plane >> 2, cls = plane & 3;
    const int inner = bid >> 3;           // 0..255
    const int yq = inner & 31;            // y-quad
    const int zc = inner >> 5;            // 0..7
    const int t = threadIdx.x;
    const int w = t >> 6;
    const int lane = t & 63;
    const int y = yq * 4 + w;             // 0..127
    const int z0 = zc * 16;
    const int xo = lane << 1;

    const float* __restrict__ xp = x + ((long)plane << 21);
    const unsigned char* __restrict__ mb = g_mask + ((long)b << 21);

    const bool ym = (y > 0), yp = (y < 127);
    const int base = (y << 7) + xo;       // row-y offset within a slice

    // raw x float2 at (slice z, row y+dy); OOB -> 0 (so 1-x = 1)
    auto ld = [&](int z, int dy, bool ok) -> float2 {
        if (!ok || (unsigned)z > 127u) return make_float2(0.f, 0.f);
        return *(const float2*)(xp + (z << 14) + base + (dy << 7));
    };

    float fp = 0.f, fn = 0.f, sx = 0.f, sy = 0.f;

#pragma unroll 1
    for (int dz = 0; dz < 16; dz += 2) {
        const int z = z0 + dz;

        // ---- 12 independent loads: slices z-1..z+2, rows y-1..y+1 ----
        float2 r0m = ld(z - 1, -1, ym), r0c = ld(z - 1, 0, true), r0p = ld(z - 1, 1, yp);
        float2 r1m = ld(z,     -1, ym), r1c = ld(z,     0, true), r1p = ld(z,     1, yp);
        float2 r2m = ld(z + 1, -1, ym), r2c = ld(z + 1, 0, true), r2p = ld(z + 1, 1, yp);
        float2 r3m = ld(z + 2, -1, ym), r3c = ld(z + 2, 0, true), r3p = ld(z + 2, 1, yp);
        const unsigned mA = *(const unsigned short*)(mb + (z << 14) + base);
        const unsigned mB = *(const unsigned short*)(mb + ((z + 1) << 14) + base);

        // ---- y-products of (1-x) per slice ----
        float2 yp0, yp1, yp2, yp3;
        yp0.x = (1.f - r0m.x) * (1.f - r0c.x) * (1.f - r0p.x);
        yp0.y = (1.f - r0m.y) * (1.f - r0c.y) * (1.f - r0p.y);
        yp1.x = (1.f - r1m.x) * (1.f - r1c.x) * (1.f - r1p.x);
        yp1.y = (1.f - r1m.y) * (1.f - r1c.y) * (1.f - r1p.y);
        yp2.x = (1.f - r2m.x) * (1.f - r2c.x) * (1.f - r2p.x);
        yp2.y = (1.f - r2m.y) * (1.f - r2c.y) * (1.f - r2p.y);
        yp3.x = (1.f - r3m.x) * (1.f - r3c.x) * (1.f - r3p.x);
        yp3.y = (1.f - r3m.y) * (1.f - r3c.y) * (1.f - r3p.y);

        // ---- z-products for the two output slices ----
        const float2 zA = make_float2(yp0.x * yp1.x * yp2.x, yp0.y * yp1.y * yp2.y);
        const float2 zB = make_float2(yp1.x * yp2.x * yp3.x, yp1.y * yp2.y * yp3.y);

        // ---- x-direction via shuffles (lane pair covers x = xo, xo+1) ----
        float lA = __shfl_up(zA.y, 1);  if (lane == 0)  lA = 1.f;
        float rA = __shfl_down(zA.x, 1); if (lane == 63) rA = 1.f;
        float lB = __shfl_up(zB.y, 1);  if (lane == 0)  lB = 1.f;
        float rB = __shfl_down(zB.x, 1); if (lane == 63) rB = 1.f;
        const float cA = zA.x * zA.y, cB = zB.x * zB.y;
        const float PA0 = lA * cA, PA1 = cA * rA;
        const float PB0 = lB * cB, PB1 = cB * rB;

        // ---- accumulate (center raw x: r1c for slice z, r2c for z+1) ----
        {
            const int m0 = mA & 0xFF, m1 = (mA >> 8) & 0xFF;
            const bool pr0 = (m0 >> cls) & 1, pr1 = (m1 >> cls) & 1;
            const bool eq0 = (m0 >> 4) == cls, eq1 = (m1 >> 4) == cls;
            sx += r1c.x + r1c.y;
            fp += eq0 ? 0.f : r1c.x * (pr0 ? 1.f : 2.f);
            fp += eq1 ? 0.f : r1c.y * (pr1 ? 1.f : 2.f);
            fn += eq0 ? (1.f - r1c.x) * (1.f + PA0) : 0.f;
            fn += eq1 ? (1.f - r1c.y) * (1.f + PA1) : 0.f;
            sy += (eq0 ? 1.f : 0.f) + (eq1 ? 1.f : 0.f);
        }
        {
            const int m0 = mB & 0xFF, m1 = (mB >> 8) & 0xFF;
            const bool pr0 = (m0 >> cls) & 1, pr1 = (m1 >> cls) & 1;
            const bool eq0 = (m0 >> 4) == cls, eq1 = (m1 >> 4) == cls;
            sx += r2c.x + r2c.y;
            fp += eq0 ? 0.f : r2c.x * (pr0 ? 1.f : 2.f);
            fp += eq1 ? 0.f : r2c.y * (pr1 ? 1.f : 2.f);
            fn += eq0 ? (1.f - r2c.x) * (1.f + PB0) : 0.f;
            fn += eq1 ? (1.f - r2c.y) * (1.f + PB1) : 0.f;
            sy += (eq0 ? 1.f : 0.f) + (eq1 ? 1.f : 0.f);
        }
    }

    // ---- reduce 4 scalars: wave shuffle -> block LDS -> global atomics ----
    float rr4[4] = {fp, fn, sx, sy};
#pragma unroll
    for (int i = 0; i < 4; ++i) {
        float vv = rr4[i];
#pragma unroll
        for (int off = 32; off >= 1; off >>= 1) vv += __shfl_down(vv, off);
        rr4[i] = vv;
    }
    if (t < 4) sred[t] = 0.f;
    __syncthreads();
    if (lane == 0) {
#pragma unroll
        for (int i = 0; i < 4; ++i) atomicAdd(&sred[i], rr4[i]);
    }
    __syncthreads();
    if (t < 4)
        atomicAdd(&acc[b * 16 + t * 4 + cls], sred[t]);
}

// ===========================================================================
// K2: finalize scalar loss
// ===========================================================================
__global__ void lah_finalize(const float* __restrict__ acc, float* __restrict__ out) {
    float loss = 0.f;
#pragma unroll
    for (int b = 0; b < 2; ++b) {
#pragma unroll
        for (int c = 1; c < 4; ++c) {
            const float fp = acc[b * 16 + 0 + c];
            const float fn = acc[b * 16 + 4 + c];
            const float sxv = acc[b * 16 + 8 + c];
            const float syv = acc[b * 16 + 12 + c];
            loss += fmaxf(fp / (sxv + EPSV), fn / (syv + EPSV));
        }
    }
    out[0] = loss / 6.f;
}

extern "C" void kernel_launch(void* const* d_in, const int* in_sizes, int n_in,
                              void* d_out, int out_size, void* d_ws, size_t ws_size,
                              hipStream_t stream) {
    const float* x = (const float*)d_in[0];
    const int* y32 = (const int*)d_in[1];
    float* out = (float*)d_out;
    float* acc = (float*)d_ws;  // 32 floats

    hipMemsetAsync(d_ws, 0, 32 * sizeof(float), stream);
    mask_build<<<K0_NBLK, 256, 0, stream>>>(y32);
    lah_flat<<<NBLK, 256, 0, stream>>>(x, acc);
    lah_finalize<<<1, 1, 0, stream>>>(acc, out);
}